// Round 1
// 124.779 us; speedup vs baseline: 1.0143x; 1.0143x over previous
//
#include <hip/hip_runtime.h>
#include <math.h>

#define BB 1024
#define LL 256
#define VV 50000
#define EE 300
#define AA 30
#define ASPLIT 2
#define APB (AA / ASPLIT)   // 15 aspects per block
#define WORD_THRES 0.2f
#define COS_EPS_F 1e-8f
#define NEG_INF_F -1e9f

// ---------------------------------------------------------------------------
// Kernel 1: cent_h[y][v] = max_{a in half y} ((cos(a,v) > thres ? cos : 0)*w[a])
// Split over aspects (max is associative): grid (391, 2) -> 782 blocks,
// ~3 blocks/CU instead of 1.5 -> 2x the waves for latency hiding, while the
// LDS-broadcast instruction count per row stays identical (15 reads/k serving
// the same 32 rows/wave). LDS drops to 18 KB/block (cap 8 blocks/CU), VGPR
// accumulators halve. row_kernel combines the two halves with one fmaxf.
// Geometry within a block unchanged: 4 lanes per vocab row (E-quarters),
// 2 rows per thread, 128 rows/block. a_emb half staged in LDS; inner-loop
// reads are 16-way broadcasts -> conflict-free.
// ---------------------------------------------------------------------------
__global__ void __launch_bounds__(256) cent_kernel(
    const float* __restrict__ w_emb,     // [V, E]
    const float* __restrict__ a_emb,     // [A, E]
    const float* __restrict__ a_weight,  // [A]
    float* __restrict__ cent)            // [ASPLIT, V]
{
    __shared__ float4 s_a[APB * 75];     // a-major: s_a[a*75 + j], 18000 B
    __shared__ float s_scale[APB];       // 1 / max(||a||, eps)
    __shared__ float s_aw[APB];

    const int t = threadIdx.x;
    const int a0 = blockIdx.y * APB;     // aspect-half base
    const float4* __restrict__ a4 = (const float4*)a_emb;   // [A][75]

    // stage this half of a_emb -> LDS (coalesced global, conflict-free LDS)
    for (int s = t; s < APB * 75; s += 256) s_a[s] = a4[a0 * 75 + s];

    // aspect norms: 8 lanes per aspect (15 aspects -> threads 0..119)
    {
        const int a = t >> 3, j = t & 7;
        if (a < APB) {
            float n2a = 0.f;
            for (int c = j; c < 75; c += 8) {
                const float4 x = a4[(a0 + a) * 75 + c];
                n2a += x.x * x.x + x.y * x.y + x.z * x.z + x.w * x.w;
            }
            n2a += __shfl_xor(n2a, 1);
            n2a += __shfl_xor(n2a, 2);
            n2a += __shfl_xor(n2a, 4);
            if (j == 0) {
                s_scale[a] = 1.f / fmaxf(sqrtf(n2a), COS_EPS_F);
                s_aw[a] = a_weight[a0 + a];
            }
        }
    }
    __syncthreads();

    const int p = t & 3;        // E-quarter lane: handles float4-cols j = 4k+p
    const int slot = t >> 2;    // 64 row-slots per block
    const int v0 = blockIdx.x * 128 + slot;   // always < VV (last block base 49920)
    const int v1 = v0 + 64;
    const bool ok1 = v1 < VV;
    const float* __restrict__ r0 = w_emb + (size_t)v0 * EE;
    const float* __restrict__ r1 = w_emb + (size_t)(ok1 ? v1 : 0) * EE;

    float acc0[APB], acc1[APB];
#pragma unroll
    for (int a = 0; a < APB; ++a) { acc0[a] = 0.f; acc1[a] = 0.f; }
    float n20 = 0.f, n21 = 0.f;

    // 75 float4 cols: k=0..17 cover j=4k+p (<=71), tail j=72+p for p<3
    for (int k = 0; k < 18; ++k) {
        const int j = 4 * k + p;
        const float4 w0 = *(const float4*)(r0 + 4 * j);
        const float4 w1 = *(const float4*)(r1 + 4 * j);
        n20 += w0.x * w0.x + w0.y * w0.y + w0.z * w0.z + w0.w * w0.w;
        n21 += w1.x * w1.x + w1.y * w1.y + w1.z * w1.z + w1.w * w1.w;
        const float4* __restrict__ ap = s_a + j;
#pragma unroll
        for (int a = 0; a < APB; ++a) {
            const float4 av = ap[a * 75];        // LDS broadcast read
            acc0[a] = fmaf(av.x, w0.x, fmaf(av.y, w0.y,
                      fmaf(av.z, w0.z, fmaf(av.w, w0.w, acc0[a]))));
            acc1[a] = fmaf(av.x, w1.x, fmaf(av.y, w1.y,
                      fmaf(av.z, w1.z, fmaf(av.w, w1.w, acc1[a]))));
        }
    }
    if (p < 3) {
        const int j = 72 + p;
        const float4 w0 = *(const float4*)(r0 + 4 * j);
        const float4 w1 = *(const float4*)(r1 + 4 * j);
        n20 += w0.x * w0.x + w0.y * w0.y + w0.z * w0.z + w0.w * w0.w;
        n21 += w1.x * w1.x + w1.y * w1.y + w1.z * w1.z + w1.w * w1.w;
        const float4* __restrict__ ap = s_a + j;
#pragma unroll
        for (int a = 0; a < APB; ++a) {
            const float4 av = ap[a * 75];
            acc0[a] = fmaf(av.x, w0.x, fmaf(av.y, w0.y,
                      fmaf(av.z, w0.z, fmaf(av.w, w0.w, acc0[a]))));
            acc1[a] = fmaf(av.x, w1.x, fmaf(av.y, w1.y,
                      fmaf(av.z, w1.z, fmaf(av.w, w1.w, acc1[a]))));
        }
    }

    // reduce partial dots across the 4-lane group (xor butterfly)
#pragma unroll
    for (int a = 0; a < APB; ++a) {
        acc0[a] += __shfl_xor(acc0[a], 1); acc0[a] += __shfl_xor(acc0[a], 2);
        acc1[a] += __shfl_xor(acc1[a], 1); acc1[a] += __shfl_xor(acc1[a], 2);
    }
    n20 += __shfl_xor(n20, 1); n20 += __shfl_xor(n20, 2);
    n21 += __shfl_xor(n21, 1); n21 += __shfl_xor(n21, 2);

    if (p == 0) {
        const float inv_x0 = 1.f / fmaxf(sqrtf(n20), COS_EPS_F);
        const float inv_x1 = 1.f / fmaxf(sqrtf(n21), COS_EPS_F);
        float m0 = 0.f, m1 = 0.f;
#pragma unroll
        for (int a = 0; a < APB; ++a) {
            const float c0 = acc0[a] * s_scale[a] * inv_x0;
            const float c1 = acc1[a] * s_scale[a] * inv_x1;
            m0 = fmaxf(m0, (c0 > WORD_THRES) ? c0 * s_aw[a] : 0.f);
            m1 = fmaxf(m1, (c1 > WORD_THRES) ? c1 * s_aw[a] : 0.f);
        }
        float* __restrict__ ch = cent + (size_t)blockIdx.y * VV;
        ch[v0] = m0;
        if (ok1) ch[v1] = m1;
    }
}

// ---------------------------------------------------------------------------
// Kernel 2: one block per batch row. 3 barriers total. Sparse z over the
// ~2-8 active positions (a_l == 0 exactly for masked positions).
// Combines the two aspect-half cent tables with one fmaxf at gather time.
// ---------------------------------------------------------------------------
__global__ void __launch_bounds__(256) row_kernel(
    const int* __restrict__ inputs,   // [B, L]
    const float* __restrict__ w_emb,  // [V, E]
    const float* __restrict__ cent,   // [ASPLIT, V]
    float* __restrict__ out)          // enc_out [B,E] | a [B,L] | cs [B]
{
    const int b = blockIdx.x;
    const int t = threadIdx.x;          // == l
    const int wid = t >> 6, lane = t & 63;

    __shared__ float pA[4], pB[4], pC[4], pD[4];
    __shared__ int s_nact;
    __shared__ int s_act_id[LL];
    __shared__ float s_act_w[LL];

    const int id = inputs[b * LL + t];
    const float c = fmaxf(cent[id], cent[VV + id]);
    const float score = (c > 0.f) ? c : NEG_INF_F;
    const float cnt = (id != 0) ? 1.f : 0.f;
    if (t == 0) s_nact = 0;

    // fused sum(c) / sum(cnt) / max(score) in one shuffle pass
    float s1 = c, s2 = cnt, s3 = score;
#pragma unroll
    for (int o = 32; o > 0; o >>= 1) {
        s1 += __shfl_down(s1, o);
        s2 += __shfl_down(s2, o);
        s3 = fmaxf(s3, __shfl_down(s3, o));
    }
    if (lane == 0) { pA[wid] = s1; pB[wid] = s2; pC[wid] = s3; }
    __syncthreads();

    const float sum_c = pA[0] + pA[1] + pA[2] + pA[3];
    const float len   = pB[0] + pB[1] + pB[2] + pB[3];
    const float mx    = fmaxf(fmaxf(pC[0], pC[1]), fmaxf(pC[2], pC[3]));

    const float p = expf(score - mx);   // expf(-1e9)==0; all-masked row -> p=1
    float s4 = p;
#pragma unroll
    for (int o = 32; o > 0; o >>= 1) s4 += __shfl_down(s4, o);
    if (lane == 0) pD[wid] = s4;
    __syncthreads();
    const float sum_p = pD[0] + pD[1] + pD[2] + pD[3];

    const float a_l = p / sum_p;
    const float cs = sum_c / (len + 1e-5f);
    const float gate = (cs > 1e-4f) ? 1.f : 0.f;

    out[BB * EE + b * LL + t] = a_l;            // attention
    if (t == 0) out[BB * EE + BB * LL + b] = cs;

    if (score > -1e8f) {                         // active <=> cent > 0
        const int i = atomicAdd(&s_nact, 1);
        s_act_id[i] = id;
        s_act_w[i] = a_l;
    }
    __syncthreads();
    const int n = s_nact;

    // z over active entries only; thread t<75 owns float4 column t
    if (t < EE / 4) {
        float4 acc = {0.f, 0.f, 0.f, 0.f};
        for (int i = 0; i < n; ++i) {
            const float wgt = s_act_w[i];
            const float4 r = *(const float4*)(w_emb + (size_t)s_act_id[i] * EE + 4 * t);
            acc.x += wgt * r.x; acc.y += wgt * r.y;
            acc.z += wgt * r.z; acc.w += wgt * r.w;
        }
        acc.x *= gate; acc.y *= gate; acc.z *= gate; acc.w *= gate;
        *(float4*)(out + b * EE + 4 * t) = acc;
    }
}

// ---------------------------------------------------------------------------
extern "C" void kernel_launch(void* const* d_in, const int* in_sizes, int n_in,
                              void* d_out, int out_size, void* d_ws, size_t ws_size,
                              hipStream_t stream) {
    const int* inputs = (const int*)d_in[0];
    const float* w_emb = (const float*)d_in[1];
    const float* a_emb = (const float*)d_in[2];
    const float* a_weight = (const float*)d_in[3];
    float* out = (float*)d_out;
    float* cent = (float*)d_ws;  // ASPLIT * 50000 floats = 400 KB scratch

    cent_kernel<<<dim3((VV + 127) / 128, ASPLIT), 256, 0, stream>>>(
        w_emb, a_emb, a_weight, cent);
    row_kernel<<<BB, 256, 0, stream>>>(inputs, w_emb, cent, out);
}

// Round 2
// 114.356 us; speedup vs baseline: 1.1067x; 1.0912x over previous
//
#include <hip/hip_runtime.h>
#include <math.h>

#define BB 1024
#define LL 256
#define VV 50000
#define EE 300
#define AA 30
#define WORD_THRES 0.2f
#define COS_EPS_F 1e-8f
#define NEG_INF_F -1e9f
#define RECHECK_DELTA 1e-3f

typedef __attribute__((ext_vector_type(8))) short bf16x8;
typedef __attribute__((ext_vector_type(4))) float f32x4;

#define MFMA16(a, b, c) __builtin_amdgcn_mfma_f32_16x16x32_bf16((a), (b), (c), 0, 0, 0)

// fp32 -> bf16 truncation split: x = hi + lo with |x - hi - lo| <~ 2^-16 |x|.
__device__ __forceinline__ unsigned pack_hi(float a, float b) {
    return (__float_as_uint(a) >> 16) | (__float_as_uint(b) & 0xFFFF0000u);
}
__device__ __forceinline__ float hi_part(float a) {
    return __uint_as_float(__float_as_uint(a) & 0xFFFF0000u);
}
__device__ __forceinline__ void cvt_hilo(const float4 f0, const float4 f1,
                                         uint4& uh, uint4& ul) {
    uh.x = pack_hi(f0.x, f0.y);
    uh.y = pack_hi(f0.z, f0.w);
    uh.z = pack_hi(f1.x, f1.y);
    uh.w = pack_hi(f1.z, f1.w);
    const float l0 = f0.x - hi_part(f0.x), l1 = f0.y - hi_part(f0.y);
    const float l2 = f0.z - hi_part(f0.z), l3 = f0.w - hi_part(f0.w);
    const float l4 = f1.x - hi_part(f1.x), l5 = f1.y - hi_part(f1.y);
    const float l6 = f1.z - hi_part(f1.z), l7 = f1.w - hi_part(f1.w);
    ul.x = pack_hi(l0, l1);
    ul.y = pack_hi(l2, l3);
    ul.z = pack_hi(l4, l5);
    ul.w = pack_hi(l6, l7);
}

// ---------------------------------------------------------------------------
// Kernel 1 (MFMA): cent[v] = max_a ((cos(a_emb[a], w_emb[v]) > thres ? cos : 0) * w[a])
// The 50000x30 cosine table is a [V,300]x[300,30] GEMM: mfma_f32_16x16x32_bf16
// with hi/lo bf16 split (3 MFMAs) gives ~2^-16 relative accuracy on cos.
// Wave = one 16-row M-tile; N=30 as two 16-col tiles; K padded 300->320 (10 steps).
// B-frags (a_emb hi/lo) built once per block into 40 KB LDS; main loop per k-step:
// 2 global dwordx4 + 4 ds_read_b128 + 6 MFMA + ~40 convert/norm VALU.
// Near-threshold values (|cos-0.2| < 1e-3, ~50 total) are re-checked in exact fp32
// so the threshold compare is bit-stable vs the fp32 reference.
// ---------------------------------------------------------------------------
__global__ void __launch_bounds__(256) cent_kernel(
    const float* __restrict__ w_emb,     // [V, E]
    const float* __restrict__ a_emb,     // [A, E]
    const float* __restrict__ a_weight,  // [A]
    float* __restrict__ cent)            // [V]
{
    __shared__ uint4 s_bfrag[40 * 64];   // [ks*4 + t*2 + (hi/lo)][lane], 40960 B
    __shared__ float s_scale[32];
    __shared__ float s_aw[32];

    const int t = threadIdx.x;
    const int l = t & 63;
    const int w = t >> 6;
    const int m = l & 15;        // A-row within tile / C-col (aspect) lane id
    const int kg = l >> 4;       // k-chunk selector (8 elements each)

    // ---- aspect inv-norms + weights (8 lanes per aspect, threads 0..239) ----
    {
        const int a = t >> 3, j = t & 7;
        if (a < AA) {
            const float4* a4 = (const float4*)a_emb + a * 75;
            float n2a = 0.f;
            for (int c = j; c < 75; c += 8) {
                const float4 x = a4[c];
                n2a += x.x * x.x + x.y * x.y + x.z * x.z + x.w * x.w;
            }
            n2a += __shfl_xor(n2a, 1);
            n2a += __shfl_xor(n2a, 2);
            n2a += __shfl_xor(n2a, 4);
            if (j == 0) {
                s_scale[a] = 1.f / fmaxf(sqrtf(n2a), COS_EPS_F);
                s_aw[a] = a_weight[a];
            }
        }
        if (t == 30 || t == 31) { s_scale[t] = 0.f; s_aw[t] = 0.f; }  // pad cols
    }

    // ---- build B fragments (a_emb hi/lo), waves split the 10 k-steps ----
    for (int ks = w; ks < 10; ks += 4) {
        const int kb = kg * 8 + 32 * ks;
#pragma unroll
        for (int tt = 0; tt < 2; ++tt) {
            const int col = tt * 16 + m;         // aspect index (pad >= 30)
            float4 f0 = {0.f, 0.f, 0.f, 0.f}, f1 = {0.f, 0.f, 0.f, 0.f};
            if (col < AA) {
                const float* ap = a_emb + col * EE;
                if (kb <= 296) f0 = *(const float4*)(ap + kb);
                if (kb <= 292) f1 = *(const float4*)(ap + kb + 4);
            }
            uint4 uh, ul;
            cvt_hilo(f0, f1, uh, ul);
            s_bfrag[(ks * 4 + tt * 2 + 0) * 64 + l] = uh;
            s_bfrag[(ks * 4 + tt * 2 + 1) * 64 + l] = ul;
        }
    }
    __syncthreads();

    // ---- main loop: one 16-row M-tile per wave ----
    const int vbase = blockIdx.x * 64 + w * 16;
    const int v = vbase + m;
    const float* __restrict__ rowp = w_emb + (size_t)((v < VV) ? v : 0) * EE;

    f32x4 acc0 = {0.f, 0.f, 0.f, 0.f};
    f32x4 acc1 = {0.f, 0.f, 0.f, 0.f};
    float n2 = 0.f;
    const uint4* __restrict__ bp0 = s_bfrag + l;

#pragma unroll 3
    for (int ks = 0; ks < 9; ++ks) {
        const int kb = kg * 8 + 32 * ks;
        const float4 f0 = *(const float4*)(rowp + kb);
        const float4 f1 = *(const float4*)(rowp + kb + 4);
        n2 = fmaf(f0.x, f0.x, fmaf(f0.y, f0.y, fmaf(f0.z, f0.z, fmaf(f0.w, f0.w, n2))));
        n2 = fmaf(f1.x, f1.x, fmaf(f1.y, f1.y, fmaf(f1.z, f1.z, fmaf(f1.w, f1.w, n2))));
        uint4 uh, ul;
        cvt_hilo(f0, f1, uh, ul);
        const bf16x8 ah = __builtin_bit_cast(bf16x8, uh);
        const bf16x8 al = __builtin_bit_cast(bf16x8, ul);
        const uint4* bp = bp0 + ks * 256;
        const bf16x8 bh0 = __builtin_bit_cast(bf16x8, bp[0]);
        const bf16x8 bl0 = __builtin_bit_cast(bf16x8, bp[64]);
        const bf16x8 bh1 = __builtin_bit_cast(bf16x8, bp[128]);
        const bf16x8 bl1 = __builtin_bit_cast(bf16x8, bp[192]);
        acc0 = MFMA16(ah, bh0, acc0);
        acc1 = MFMA16(ah, bh1, acc1);
        acc0 = MFMA16(ah, bl0, acc0);
        acc1 = MFMA16(ah, bl1, acc1);
        acc0 = MFMA16(al, bh0, acc0);
        acc1 = MFMA16(al, bh1, acc1);
    }
    {   // ks = 9 (k = 288..299 valid, 300..319 zero-padded)
        const int kb = kg * 8 + 288;
        float4 f0 = {0.f, 0.f, 0.f, 0.f}, f1 = {0.f, 0.f, 0.f, 0.f};
        if (kb <= 296) f0 = *(const float4*)(rowp + kb);
        if (kb <= 292) f1 = *(const float4*)(rowp + kb + 4);
        n2 = fmaf(f0.x, f0.x, fmaf(f0.y, f0.y, fmaf(f0.z, f0.z, fmaf(f0.w, f0.w, n2))));
        n2 = fmaf(f1.x, f1.x, fmaf(f1.y, f1.y, fmaf(f1.z, f1.z, fmaf(f1.w, f1.w, n2))));
        uint4 uh, ul;
        cvt_hilo(f0, f1, uh, ul);
        const bf16x8 ah = __builtin_bit_cast(bf16x8, uh);
        const bf16x8 al = __builtin_bit_cast(bf16x8, ul);
        const uint4* bp = bp0 + 9 * 256;
        const bf16x8 bh0 = __builtin_bit_cast(bf16x8, bp[0]);
        const bf16x8 bl0 = __builtin_bit_cast(bf16x8, bp[64]);
        const bf16x8 bh1 = __builtin_bit_cast(bf16x8, bp[128]);
        const bf16x8 bl1 = __builtin_bit_cast(bf16x8, bp[192]);
        acc0 = MFMA16(ah, bh0, acc0);
        acc1 = MFMA16(ah, bh1, acc1);
        acc0 = MFMA16(ah, bl0, acc0);
        acc1 = MFMA16(ah, bl1, acc1);
        acc0 = MFMA16(al, bh0, acc0);
        acc1 = MFMA16(al, bh1, acc1);
    }

    // ---- epilogue ----
    // n2 partial covers row m, k-quarter kg: full norm via xor over kg bits
    n2 += __shfl_xor(n2, 16);
    n2 += __shfl_xor(n2, 32);
    // C/D layout: lane l holds D[rows kg*4+j][col m (+16 for acc1)]

    const float sc0 = s_scale[m], aw0 = s_aw[m];
    const float sc1 = s_scale[16 + m], aw1 = s_aw[16 + m];
    const bool col1ok = (16 + m) < AA;
    float mx[4];
#pragma unroll
    for (int j = 0; j < 4; ++j) {
        const int r = kg * 4 + j;                 // row within tile
        const float n2r = __int_as_float(
            __builtin_amdgcn_ds_bpermute(r << 2, __float_as_int(n2)));
        const float inv_x = 1.f / fmaxf(sqrtf(n2r), COS_EPS_F);
        float c0 = acc0[j] * sc0 * inv_x;
        float c1 = acc1[j] * sc1 * inv_x;
        // exact fp32 recheck for near-threshold cos values (rare: ~50 globally)
        if (fabsf(c0 - WORD_THRES) < RECHECK_DELTA) {
            const int rr = vbase + r;
            const float* wr = w_emb + (size_t)((rr < VV) ? rr : 0) * EE;
            const float* ar = a_emb + m * EE;
            float d = 0.f;
            for (int k = 0; k < EE; ++k) d = fmaf(wr[k], ar[k], d);
            c0 = d * sc0 * inv_x;
        }
        if (col1ok && fabsf(c1 - WORD_THRES) < RECHECK_DELTA) {
            const int rr = vbase + r;
            const float* wr = w_emb + (size_t)((rr < VV) ? rr : 0) * EE;
            const float* ar = a_emb + (16 + m) * EE;
            float d = 0.f;
            for (int k = 0; k < EE; ++k) d = fmaf(wr[k], ar[k], d);
            c1 = d * sc1 * inv_x;
        }
        float mj = fmaxf((c0 > WORD_THRES) ? c0 * aw0 : 0.f,
                         (c1 > WORD_THRES) ? c1 * aw1 : 0.f);
        mj = fmaxf(mj, __shfl_xor(mj, 1));
        mj = fmaxf(mj, __shfl_xor(mj, 2));
        mj = fmaxf(mj, __shfl_xor(mj, 4));
        mj = fmaxf(mj, __shfl_xor(mj, 8));
        mx[j] = mj;
    }
    if (m == 0 && vbase < VV) {
        const float4 o = {mx[0], mx[1], mx[2], mx[3]};
        *(float4*)(cent + vbase + kg * 4) = o;   // rows kg*4..kg*4+3, 16B aligned
    }
}

// ---------------------------------------------------------------------------
// Kernel 2: one block per batch row. 3 barriers total. Sparse z over the
// ~2-8 active positions (a_l == 0 exactly for masked positions).
// ---------------------------------------------------------------------------
__global__ void __launch_bounds__(256) row_kernel(
    const int* __restrict__ inputs,   // [B, L]
    const float* __restrict__ w_emb,  // [V, E]
    const float* __restrict__ cent,   // [V]
    float* __restrict__ out)          // enc_out [B,E] | a [B,L] | cs [B]
{
    const int b = blockIdx.x;
    const int t = threadIdx.x;          // == l
    const int wid = t >> 6, lane = t & 63;

    __shared__ float pA[4], pB[4], pC[4], pD[4];
    __shared__ int s_nact;
    __shared__ int s_act_id[LL];
    __shared__ float s_act_w[LL];

    const int id = inputs[b * LL + t];
    const float c = cent[id];
    const float score = (c > 0.f) ? c : NEG_INF_F;
    const float cnt = (id != 0) ? 1.f : 0.f;
    if (t == 0) s_nact = 0;

    // fused sum(c) / sum(cnt) / max(score) in one shuffle pass
    float s1 = c, s2 = cnt, s3 = score;
#pragma unroll
    for (int o = 32; o > 0; o >>= 1) {
        s1 += __shfl_down(s1, o);
        s2 += __shfl_down(s2, o);
        s3 = fmaxf(s3, __shfl_down(s3, o));
    }
    if (lane == 0) { pA[wid] = s1; pB[wid] = s2; pC[wid] = s3; }
    __syncthreads();

    const float sum_c = pA[0] + pA[1] + pA[2] + pA[3];
    const float len   = pB[0] + pB[1] + pB[2] + pB[3];
    const float mx    = fmaxf(fmaxf(pC[0], pC[1]), fmaxf(pC[2], pC[3]));

    const float p = expf(score - mx);   // expf(-1e9)==0; all-masked row -> p=1
    float s4 = p;
#pragma unroll
    for (int o = 32; o > 0; o >>= 1) s4 += __shfl_down(s4, o);
    if (lane == 0) pD[wid] = s4;
    __syncthreads();
    const float sum_p = pD[0] + pD[1] + pD[2] + pD[3];

    const float a_l = p / sum_p;
    const float cs = sum_c / (len + 1e-5f);
    const float gate = (cs > 1e-4f) ? 1.f : 0.f;

    out[BB * EE + b * LL + t] = a_l;            // attention
    if (t == 0) out[BB * EE + BB * LL + b] = cs;

    if (score > -1e8f) {                         // active <=> cent > 0
        const int i = atomicAdd(&s_nact, 1);
        s_act_id[i] = id;
        s_act_w[i] = a_l;
    }
    __syncthreads();
    const int n = s_nact;

    // z over active entries only; thread t<75 owns float4 column t
    if (t < EE / 4) {
        float4 acc = {0.f, 0.f, 0.f, 0.f};
        for (int i = 0; i < n; ++i) {
            const float wgt = s_act_w[i];
            const float4 r = *(const float4*)(w_emb + (size_t)s_act_id[i] * EE + 4 * t);
            acc.x += wgt * r.x; acc.y += wgt * r.y;
            acc.z += wgt * r.z; acc.w += wgt * r.w;
        }
        acc.x *= gate; acc.y *= gate; acc.z *= gate; acc.w *= gate;
        *(float4*)(out + b * EE + 4 * t) = acc;
    }
}

// ---------------------------------------------------------------------------
extern "C" void kernel_launch(void* const* d_in, const int* in_sizes, int n_in,
                              void* d_out, int out_size, void* d_ws, size_t ws_size,
                              hipStream_t stream) {
    const int* inputs = (const int*)d_in[0];
    const float* w_emb = (const float*)d_in[1];
    const float* a_emb = (const float*)d_in[2];
    const float* a_weight = (const float*)d_in[3];
    float* out = (float*)d_out;
    float* cent = (float*)d_ws;  // 50000 floats = 200 KB scratch

    cent_kernel<<<(VV + 63) / 64, 256, 0, stream>>>(w_emb, a_emb, a_weight, cent);
    row_kernel<<<BB, 256, 0, stream>>>(inputs, w_emb, cent, out);
}

// Round 3
// 111.041 us; speedup vs baseline: 1.1397x; 1.0299x over previous
//
#include <hip/hip_runtime.h>
#include <math.h>

#define BB 1024
#define LL 256
#define VV 50000
#define EE 300
#define AA 30
#define WORD_THRES 0.2f
#define COS_EPS_F 1e-8f
#define NEG_INF_F -1e9f
#define RECHECK_DELTA 2e-4f

typedef __attribute__((ext_vector_type(8))) short bf16x8;
typedef __attribute__((ext_vector_type(4))) float f32x4;

#define MFMA16(a, b, c) __builtin_amdgcn_mfma_f32_16x16x32_bf16((a), (b), (c), 0, 0, 0)

// fp32 -> bf16 truncation split: x = hi + lo with |x - hi - lo| <~ 2^-17 |x|.
__device__ __forceinline__ unsigned pack_hi(float a, float b) {
    return (__float_as_uint(a) >> 16) | (__float_as_uint(b) & 0xFFFF0000u);
}
__device__ __forceinline__ float hi_part(float a) {
    return __uint_as_float(__float_as_uint(a) & 0xFFFF0000u);
}
__device__ __forceinline__ void cvt_hilo(const float4 f0, const float4 f1,
                                         uint4& uh, uint4& ul) {
    uh.x = pack_hi(f0.x, f0.y);
    uh.y = pack_hi(f0.z, f0.w);
    uh.z = pack_hi(f1.x, f1.y);
    uh.w = pack_hi(f1.z, f1.w);
    const float l0 = f0.x - hi_part(f0.x), l1 = f0.y - hi_part(f0.y);
    const float l2 = f0.z - hi_part(f0.z), l3 = f0.w - hi_part(f0.w);
    const float l4 = f1.x - hi_part(f1.x), l5 = f1.y - hi_part(f1.y);
    const float l6 = f1.z - hi_part(f1.z), l7 = f1.w - hi_part(f1.w);
    ul.x = pack_hi(l0, l1);
    ul.y = pack_hi(l2, l3);
    ul.z = pack_hi(l4, l5);
    ul.w = pack_hi(l6, l7);
}

// clamped pair load: safe addresses for the zero-padded tail k-step
__device__ __forceinline__ void ld_pair(const float* __restrict__ rowp, int kb,
                                        float4& a, float4& b) {
    const int k0 = (kb > 296) ? 296 : kb;
    const int k1 = (kb + 4 > 296) ? 296 : (kb + 4);
    a = *(const float4*)(rowp + k0);
    b = *(const float4*)(rowp + k1);
}

// ---------------------------------------------------------------------------
// Kernel 1 (MFMA): cent[v] = max_a ((cos(a_emb[a], w_emb[v]) > thres ? cos : 0) * w[a])
// [V,300]x[300,30] GEMM via mfma_f32_16x16x32_bf16 with hi/lo bf16 split
// (3 MFMAs, ~1e-5 relative accuracy on cos). Wave = one 16-row M-tile,
// N=30 as two 16-col tiles, K padded 300->320 (10 steps).
// Main loop is a 5-deep register ring: prologue bursts 10 dwordx4 (5 steps),
// each iteration prefetches step i+5 before processing step i -> ~10-12
// global loads in flight per wave to cover L3/HBM latency (round-2 version
// kept only ~4 in flight and ran 3x over the HBM floor).
// Near-threshold cos (|cos-0.2| < 2e-4, ~10 globally) re-checked in exact fp32.
// ---------------------------------------------------------------------------
__global__ void __launch_bounds__(256) cent_kernel(
    const float* __restrict__ w_emb,     // [V, E]
    const float* __restrict__ a_emb,     // [A, E]
    const float* __restrict__ a_weight,  // [A]
    float* __restrict__ cent)            // [V]
{
    __shared__ uint4 s_bfrag[40 * 64];   // [ks*4 + t*2 + (hi/lo)][lane], 40960 B
    __shared__ float s_scale[32];
    __shared__ float s_aw[32];

    const int t = threadIdx.x;
    const int l = t & 63;
    const int w = t >> 6;
    const int m = l & 15;        // row within tile / aspect lane id
    const int kg = l >> 4;       // k-chunk selector (8 elements each)

    // ---- aspect inv-norms + weights (8 lanes per aspect, threads 0..239) ----
    {
        const int a = t >> 3, j = t & 7;
        if (a < AA) {
            const float4* a4 = (const float4*)a_emb + a * 75;
            float n2a = 0.f;
            for (int c = j; c < 75; c += 8) {
                const float4 x = a4[c];
                n2a += x.x * x.x + x.y * x.y + x.z * x.z + x.w * x.w;
            }
            n2a += __shfl_xor(n2a, 1);
            n2a += __shfl_xor(n2a, 2);
            n2a += __shfl_xor(n2a, 4);
            if (j == 0) {
                s_scale[a] = 1.f / fmaxf(sqrtf(n2a), COS_EPS_F);
                s_aw[a] = a_weight[a];
            }
        }
        if (t == 30 || t == 31) { s_scale[t] = 0.f; s_aw[t] = 0.f; }  // pad cols
    }

    // ---- build B fragments (a_emb hi/lo), waves split the 10 k-steps ----
    for (int ks = w; ks < 10; ks += 4) {
        const int kb = kg * 8 + 32 * ks;
#pragma unroll
        for (int tt = 0; tt < 2; ++tt) {
            const int col = tt * 16 + m;         // aspect index (pad >= 30)
            float4 f0 = {0.f, 0.f, 0.f, 0.f}, f1 = {0.f, 0.f, 0.f, 0.f};
            if (col < AA) {
                const float* ap = a_emb + col * EE;
                if (kb <= 296) f0 = *(const float4*)(ap + kb);
                if (kb <= 292) f1 = *(const float4*)(ap + kb + 4);
            }
            uint4 uh, ul;
            cvt_hilo(f0, f1, uh, ul);
            s_bfrag[(ks * 4 + tt * 2 + 0) * 64 + l] = uh;
            s_bfrag[(ks * 4 + tt * 2 + 1) * 64 + l] = ul;
        }
    }
    __syncthreads();

    // ---- main loop: one 16-row M-tile per wave, 5-deep load ring ----
    const int vbase = blockIdx.x * 64 + w * 16;
    const int v = vbase + m;
    const float* __restrict__ rowp = w_emb + (size_t)((v < VV) ? v : 0) * EE;

    f32x4 acc0 = {0.f, 0.f, 0.f, 0.f};
    f32x4 acc1 = {0.f, 0.f, 0.f, 0.f};
    float n2 = 0.f;
    const uint4* __restrict__ bp0 = s_bfrag + l;

    float4 pa[5], pb[5];
#pragma unroll
    for (int i = 0; i < 5; ++i)
        ld_pair(rowp, kg * 8 + 32 * i, pa[i], pb[i]);

#pragma unroll
    for (int i = 0; i < 10; ++i) {
        const int s = i % 5;                       // static under full unroll
        float4 f0 = pa[s], f1 = pb[s];
        if (i < 5)                                 // prefetch step i+5
            ld_pair(rowp, kg * 8 + 32 * (i + 5), pa[s], pb[s]);
        if (i == 9) {                              // zero-padded tail lanes
            const float4 z = {0.f, 0.f, 0.f, 0.f};
            if (kg >= 2) f0 = z;                   // kb=304/312: out of row
            if (kg >= 1) f1 = z;                   // kb+4>=300
        }
        n2 = fmaf(f0.x, f0.x, fmaf(f0.y, f0.y, fmaf(f0.z, f0.z, fmaf(f0.w, f0.w, n2))));
        n2 = fmaf(f1.x, f1.x, fmaf(f1.y, f1.y, fmaf(f1.z, f1.z, fmaf(f1.w, f1.w, n2))));
        uint4 uh, ul;
        cvt_hilo(f0, f1, uh, ul);
        const bf16x8 ah = __builtin_bit_cast(bf16x8, uh);
        const bf16x8 al = __builtin_bit_cast(bf16x8, ul);
        const uint4* bp = bp0 + i * 256;
        const bf16x8 bh0 = __builtin_bit_cast(bf16x8, bp[0]);
        const bf16x8 bl0 = __builtin_bit_cast(bf16x8, bp[64]);
        const bf16x8 bh1 = __builtin_bit_cast(bf16x8, bp[128]);
        const bf16x8 bl1 = __builtin_bit_cast(bf16x8, bp[192]);
        acc0 = MFMA16(ah, bh0, acc0);
        acc1 = MFMA16(ah, bh1, acc1);
        acc0 = MFMA16(ah, bl0, acc0);
        acc1 = MFMA16(ah, bl1, acc1);
        acc0 = MFMA16(al, bh0, acc0);
        acc1 = MFMA16(al, bh1, acc1);
    }

    // ---- epilogue ----
    n2 += __shfl_xor(n2, 16);
    n2 += __shfl_xor(n2, 32);
    // C/D layout: lane l holds D[rows kg*4+j][col m (+16 for acc1)]

    const float sc0 = s_scale[m], aw0 = s_aw[m];
    const float sc1 = s_scale[16 + m], aw1 = s_aw[16 + m];
    const bool col1ok = (16 + m) < AA;
    float mx[4];
#pragma unroll
    for (int j = 0; j < 4; ++j) {
        const int r = kg * 4 + j;                 // row within tile
        const float n2r = __int_as_float(
            __builtin_amdgcn_ds_bpermute(r << 2, __float_as_int(n2)));
        const float inv_x = 1.f / fmaxf(sqrtf(n2r), COS_EPS_F);
        float c0 = acc0[j] * sc0 * inv_x;
        float c1 = acc1[j] * sc1 * inv_x;
        // exact fp32 recheck for near-threshold cos values (rare: ~10 globally)
        if (fabsf(c0 - WORD_THRES) < RECHECK_DELTA) {
            const int rr = vbase + r;
            const float* wr = w_emb + (size_t)((rr < VV) ? rr : 0) * EE;
            const float* ar = a_emb + m * EE;
            float d = 0.f;
            for (int k = 0; k < EE; ++k) d = fmaf(wr[k], ar[k], d);
            c0 = d * sc0 * inv_x;
        }
        if (col1ok && fabsf(c1 - WORD_THRES) < RECHECK_DELTA) {
            const int rr = vbase + r;
            const float* wr = w_emb + (size_t)((rr < VV) ? rr : 0) * EE;
            const float* ar = a_emb + (16 + m) * EE;
            float d = 0.f;
            for (int k = 0; k < EE; ++k) d = fmaf(wr[k], ar[k], d);
            c1 = d * sc1 * inv_x;
        }
        float mj = fmaxf((c0 > WORD_THRES) ? c0 * aw0 : 0.f,
                         (c1 > WORD_THRES) ? c1 * aw1 : 0.f);
        mj = fmaxf(mj, __shfl_xor(mj, 1));
        mj = fmaxf(mj, __shfl_xor(mj, 2));
        mj = fmaxf(mj, __shfl_xor(mj, 4));
        mj = fmaxf(mj, __shfl_xor(mj, 8));
        mx[j] = mj;
    }
    if (m == 0 && vbase < VV) {
        const float4 o = {mx[0], mx[1], mx[2], mx[3]};
        *(float4*)(cent + vbase + kg * 4) = o;   // rows kg*4..kg*4+3
    }
}

// ---------------------------------------------------------------------------
// Kernel 2: ONE WAVE per batch row (4 rows/block, 256 blocks). Lane owns 4
// contiguous positions -> int4 input load, 4 cent gathers, all reductions as
// one 6-level shuffle butterfly (no LDS round-trips), coalesced float4
// attention write. One barrier total (orders the per-wave active lists).
// Sparse z over the ~2 active positions per row.
// ---------------------------------------------------------------------------
__global__ void __launch_bounds__(256) row_kernel(
    const int* __restrict__ inputs,   // [B, L]
    const float* __restrict__ w_emb,  // [V, E]
    const float* __restrict__ cent,   // [V]
    float* __restrict__ out)          // enc_out [B,E] | a [B,L] | cs [B]
{
    const int w = threadIdx.x >> 6;
    const int lane = threadIdx.x & 63;
    const int b = blockIdx.x * 4 + w;           // wave-per-row

    __shared__ int s_id[4][LL];
    __shared__ float s_w[4][LL];
    __shared__ int s_n[4];

    if (lane == 0) s_n[w] = 0;

    const int4 id4 = *(const int4*)(inputs + b * LL + lane * 4);
    const float c0 = cent[id4.x];
    const float c1 = cent[id4.y];
    const float c2 = cent[id4.z];
    const float c3 = cent[id4.w];
    const float sc0 = (c0 > 0.f) ? c0 : NEG_INF_F;
    const float sc1 = (c1 > 0.f) ? c1 : NEG_INF_F;
    const float sc2 = (c2 > 0.f) ? c2 : NEG_INF_F;
    const float sc3 = (c3 > 0.f) ? c3 : NEG_INF_F;

    float s1 = c0 + c1 + c2 + c3;                             // sum cent
    float s2 = (id4.x != 0 ? 1.f : 0.f) + (id4.y != 0 ? 1.f : 0.f) +
               (id4.z != 0 ? 1.f : 0.f) + (id4.w != 0 ? 1.f : 0.f);
    float s3 = fmaxf(fmaxf(sc0, sc1), fmaxf(sc2, sc3));       // max score
#pragma unroll
    for (int o = 1; o < 64; o <<= 1) {
        s1 += __shfl_xor(s1, o);
        s2 += __shfl_xor(s2, o);
        s3 = fmaxf(s3, __shfl_xor(s3, o));
    }
    const float mx = s3;

    const float p0 = expf(sc0 - mx);
    const float p1 = expf(sc1 - mx);
    const float p2 = expf(sc2 - mx);
    const float p3 = expf(sc3 - mx);
    float s4 = p0 + p1 + p2 + p3;
#pragma unroll
    for (int o = 1; o < 64; o <<= 1) s4 += __shfl_xor(s4, o);

    const float rinv = 1.f / s4;
    const float4 av = {p0 * rinv, p1 * rinv, p2 * rinv, p3 * rinv};
    *(float4*)(out + BB * EE + b * LL + lane * 4) = av;       // attention

    const float cs = s1 / (s2 + 1e-5f);
    const float gate = (cs > 1e-4f) ? 1.f : 0.f;
    if (lane == 0) out[BB * EE + BB * LL + b] = cs;

    // per-wave active list (score > -1e8 <=> cent > 0)
    if (sc0 > -1e8f) { const int i = atomicAdd(&s_n[w], 1); s_id[w][i] = id4.x; s_w[w][i] = av.x; }
    if (sc1 > -1e8f) { const int i = atomicAdd(&s_n[w], 1); s_id[w][i] = id4.y; s_w[w][i] = av.y; }
    if (sc2 > -1e8f) { const int i = atomicAdd(&s_n[w], 1); s_id[w][i] = id4.z; s_w[w][i] = av.z; }
    if (sc3 > -1e8f) { const int i = atomicAdd(&s_n[w], 1); s_id[w][i] = id4.w; s_w[w][i] = av.w; }
    __syncthreads();                              // order LDS list vs reads
    const int n = s_n[w];

    // z over active entries; lane owns float4 col lane (+ col 64+lane if <11)
    float4 accA = {0.f, 0.f, 0.f, 0.f};
    float4 accB = {0.f, 0.f, 0.f, 0.f};
    for (int i = 0; i < n; ++i) {
        const float wgt = s_w[w][i];
        const float4* rp = (const float4*)(w_emb + (size_t)s_id[w][i] * EE);
        const float4 ra = rp[lane];
        accA.x += wgt * ra.x; accA.y += wgt * ra.y;
        accA.z += wgt * ra.z; accA.w += wgt * ra.w;
        if (lane < 11) {
            const float4 rb = rp[64 + lane];
            accB.x += wgt * rb.x; accB.y += wgt * rb.y;
            accB.z += wgt * rb.z; accB.w += wgt * rb.w;
        }
    }
    accA.x *= gate; accA.y *= gate; accA.z *= gate; accA.w *= gate;
    *(float4*)(out + b * EE + 4 * lane) = accA;
    if (lane < 11) {
        accB.x *= gate; accB.y *= gate; accB.z *= gate; accB.w *= gate;
        *(float4*)(out + b * EE + 256 + 4 * lane) = accB;
    }
}

// ---------------------------------------------------------------------------
extern "C" void kernel_launch(void* const* d_in, const int* in_sizes, int n_in,
                              void* d_out, int out_size, void* d_ws, size_t ws_size,
                              hipStream_t stream) {
    const int* inputs = (const int*)d_in[0];
    const float* w_emb = (const float*)d_in[1];
    const float* a_emb = (const float*)d_in[2];
    const float* a_weight = (const float*)d_in[3];
    float* out = (float*)d_out;
    float* cent = (float*)d_ws;  // 50000 floats = 200 KB scratch

    cent_kernel<<<(VV + 63) / 64, 256, 0, stream>>>(w_emb, a_emb, a_weight, cent);
    row_kernel<<<BB / 4, 256, 0, stream>>>(inputs, w_emb, cent, out);
}